// Round 12
// baseline (56.849 us; speedup 1.0000x reference)
//
#include <hip/hip_runtime.h>
#include <hip/hip_bf16.h>

// Problem constants
#define B_  64
#define N1_ 8
#define KK  128
#define EE  256
#define HH  512
#define BN  (B_ * N1_)   // 512
#define LOG2E 1.4426950408889634f

typedef __attribute__((ext_vector_type(8))) short short8;   // bf16x8 MFMA frag
typedef __attribute__((ext_vector_type(4))) float f32x4;    // MFMA acc

__device__ __forceinline__ short bfs(float f) {
  __hip_bfloat16 h = __float2bfloat16(f);   // RNE
  return __builtin_bit_cast(short, h);
}
__device__ __forceinline__ float bf2f(short s) {
  unsigned int u = ((unsigned int)(unsigned short)s) << 16;
  return __builtin_bit_cast(float, u);
}
__device__ __forceinline__ float tanhf_fast(float x) {
  float e2 = __builtin_amdgcn_exp2f(2.8853900817779268f * x);  // exp(2x)
  return 1.0f - 2.0f * __builtin_amdgcn_rcpf(e2 + 1.0f);
}
__device__ __forceinline__ float exp_f(float x) {             // e^x
  return __builtin_amdgcn_exp2f(x * LOG2E);
}

// ---------------------------------------------------------------------------
// k_prep:
//  blocks 0..63   -> wk_w -> FRAGMENT-MAJOR bf16 wk_fr:
//     chunk ((ht*8+s)*64 + lane)[8] = wk[ht*16+(lane&15)][(lane>>4)*8+s*32..]
//  blocks 64..127 -> qproj MFMA: qp[bn][h] = q.wq[h] + wq_b[h] + wk_b[h]
// MFMA frag [m89]: A row=lane&15, e=(lane>>4)*8+s*32; D col=lane&15,
// row=(lane>>4)*4+reg.
// ---------------------------------------------------------------------------
__global__ __launch_bounds__(256) void k_prep(
    const float* __restrict__ wk_w,
    const float* __restrict__ queries,
    const float* __restrict__ wq_w,
    const float* __restrict__ wq_b,
    const float* __restrict__ wk_b,
    unsigned short* __restrict__ wk_fr,
    float* __restrict__ qp) {
  const int bid = blockIdx.x, t = threadIdx.x;
  if (bid < 64) {
    const int g  = bid * 256 + t;           // chunk id 0..16383
    const int h  = g >> 5;
    const int e0 = (g & 31) * 8;
    float4 x = *(const float4*)(wk_w + (size_t)h * EE + e0);
    float4 y = *(const float4*)(wk_w + (size_t)h * EE + e0 + 4);
    short8 f;
    f[0] = bfs(x.x); f[1] = bfs(x.y); f[2] = bfs(x.z); f[3] = bfs(x.w);
    f[4] = bfs(y.x); f[5] = bfs(y.y); f[6] = bfs(y.z); f[7] = bfs(y.w);
    const int ht = h >> 4, hl = h & 15;
    const int s = e0 >> 5, lg = (e0 >> 3) & 3;
    const int chunk = (ht * 8 + s) * 64 + lg * 16 + hl;
    *(short8*)(wk_fr + (size_t)chunk * 8) = f;
  } else {
    const int w = t >> 6, l = t & 63, lg = l >> 4, ll = l & 15;
    const int g2 = bid - 64;                // 0..63
    const int bn0 = (g2 >> 1) * 16;
    const int ht0 = (g2 & 1) * 16;
    short8 af[8];
    {
      const float* qr = queries + (size_t)(bn0 + ll) * EE + lg * 8;
      #pragma unroll
      for (int s = 0; s < 8; ++s) {
        float4 x = *(const float4*)(qr + s * 32);
        float4 y = *(const float4*)(qr + s * 32 + 4);
        short8 f;
        f[0] = bfs(x.x); f[1] = bfs(x.y); f[2] = bfs(x.z); f[3] = bfs(x.w);
        f[4] = bfs(y.x); f[5] = bfs(y.y); f[6] = bfs(y.z); f[7] = bfs(y.w);
        af[s] = f;
      }
    }
    #pragma unroll
    for (int i = 0; i < 4; ++i) {
      const int ht = ht0 + w * 4 + i;
      const float* bp = wq_w + (size_t)(ht * 16 + ll) * EE + lg * 8;
      f32x4 a = {0.f, 0.f, 0.f, 0.f};
      #pragma unroll
      for (int s = 0; s < 8; ++s) {
        float4 x = *(const float4*)(bp + s * 32);
        float4 y = *(const float4*)(bp + s * 32 + 4);
        short8 f;
        f[0] = bfs(x.x); f[1] = bfs(x.y); f[2] = bfs(x.z); f[3] = bfs(x.w);
        f[4] = bfs(y.x); f[5] = bfs(y.y); f[6] = bfs(y.z); f[7] = bfs(y.w);
        a = __builtin_amdgcn_mfma_f32_16x16x32_bf16(af[s], f, a, 0, 0, 0);
      }
      const int h = ht * 16 + ll;
      const float add = wq_b[h] + wk_b[h];
      #pragma unroll
      for (int r = 0; r < 4; ++r)
        qp[(size_t)(bn0 + lg * 4 + r) * HH + h] = a[r] + add;
    }
  }
}

// ---------------------------------------------------------------------------
// k_scorespv: grid 1024 = 512 bn x 2; block = 128 thr = 2 waves; wave owns
// 32 key-rows (group g = (bid&1)*2 + w), covers ALL 512 h. Keys are read
// ONCE (A-frags in regs) and the partial PV is computed IN-REGISTER:
//   per wave: masked scores -> m_g, l_g, o_g[e] = sum_rows e^{s-m_g}*keys.
// No main-loop barriers; 8 independent waves/CU tile the HBM stream.
// B register-dbuf from fragment-major wk_fr (contiguous 1 KB wave-reads).
// MFMA 16x16x32 C/D: col(h)=lane&15, row(key)=(lane>>4)*4+reg   [m89].
// ---------------------------------------------------------------------------
__global__ __launch_bounds__(128, 2) void k_scorespv(
    const float* __restrict__ keys,
    const unsigned short* __restrict__ wk_fr,
    const float* __restrict__ wv_w,
    const float* __restrict__ qp,
    const int* __restrict__ masks,
    float* __restrict__ o_part,     // [bn][4][256]
    float* __restrict__ ml_part,    // [bn][4][2]  {m, l}
    float* __restrict__ smask) {    // [bn][128] masked scores
  const int t  = threadIdx.x;
  const int w  = t >> 6;       // wave 0..1
  const int l  = t & 63;
  const int lg = l >> 4;       // lane group 0..3
  const int ll = l & 15;
  const int bid = blockIdx.x;
  const int bn  = bid >> 1;
  const int g   = (bid & 1) * 2 + w;   // row-group 0..3
  const int row0 = g * 32;
  const short8* wkf = (const short8*)wk_fr;

  __shared__ float sc_l[2][32];

  // A-frags: this wave's 32 rows of keys -> bf16, kept in regs for PV too
  short8 af0[8], af1[8];
  {
    const float* kp0 = keys + (size_t)(bn * KK + row0 + ll) * EE + lg * 8;
    const float* kp1 = kp0 + 16 * EE;
    #pragma unroll
    for (int s = 0; s < 8; ++s) {
      float4 x = *(const float4*)(kp0 + s * 32);
      float4 y = *(const float4*)(kp0 + s * 32 + 4);
      short8 f;
      f[0] = bfs(x.x); f[1] = bfs(x.y); f[2] = bfs(x.z); f[3] = bfs(x.w);
      f[4] = bfs(y.x); f[5] = bfs(y.y); f[6] = bfs(y.z); f[7] = bfs(y.w);
      af0[s] = f;
      x = *(const float4*)(kp1 + s * 32);
      y = *(const float4*)(kp1 + s * 32 + 4);
      f[0] = bfs(x.x); f[1] = bfs(x.y); f[2] = bfs(x.z); f[3] = bfs(x.w);
      f[4] = bfs(y.x); f[5] = bfs(y.y); f[6] = bfs(y.z); f[7] = bfs(y.w);
      af1[s] = f;
    }
  }

  float p0[4] = {0.f, 0.f, 0.f, 0.f};
  float p1[4] = {0.f, 0.f, 0.f, 0.f};
  short8 bA[8], bB[8];

#define LOADB(dst, ht) {                                                   \
    _Pragma("unroll") for (int s = 0; s < 8; ++s)                          \
      dst[s] = wkf[((ht) * 8 + s) * 64 + l]; }

#define COMPUTE(cur, ii) {                                                 \
    f32x4 a0 = {0.f, 0.f, 0.f, 0.f};                                       \
    f32x4 a1 = {0.f, 0.f, 0.f, 0.f};                                       \
    __builtin_amdgcn_s_setprio(1);                                         \
    _Pragma("unroll") for (int s = 0; s < 8; ++s) {                        \
      a0 = __builtin_amdgcn_mfma_f32_16x16x32_bf16(af0[s], cur[s], a0, 0, 0, 0); \
      a1 = __builtin_amdgcn_mfma_f32_16x16x32_bf16(af1[s], cur[s], a1, 0, 0, 0); } \
    __builtin_amdgcn_s_setprio(0);                                         \
    const int h = (ii) * 16 + ll;                                          \
    const float qb = qp[(size_t)bn * HH + h];                              \
    const float wv = wv_w[h];                                              \
    _Pragma("unroll") for (int r = 0; r < 4; ++r) {                        \
      p0[r] += wv * tanhf_fast(a0[r] + qb);                                \
      p1[r] += wv * tanhf_fast(a1[r] + qb); } }

  LOADB(bA, 0);
  __builtin_amdgcn_sched_barrier(0);
  #pragma unroll 1
  for (int i = 0; i < 32; i += 2) {
    LOADB(bB, i + 1);
    __builtin_amdgcn_sched_barrier(0);
    COMPUTE(bA, i);
    if (i < 30) {
      LOADB(bA, i + 2);
      __builtin_amdgcn_sched_barrier(0);
    }
    COMPUTE(bB, i + 1);
  }
#undef COMPUTE
#undef LOADB

  // score reduce over h (16 ll lanes per group)
  #pragma unroll
  for (int r = 0; r < 4; ++r) {
    #pragma unroll
    for (int off = 1; off <= 8; off <<= 1) {
      p0[r] += __shfl_xor(p0[r], off, 64);
      p1[r] += __shfl_xor(p1[r], off, 64);
    }
  }
  // redistribute: score[row] -> lanes with ll == row&15
  if (ll == 0) {
    #pragma unroll
    for (int r = 0; r < 4; ++r) {
      sc_l[w][lg * 4 + r]      = p0[r];
      sc_l[w][16 + lg * 4 + r] = p1[r];
    }
  }
  __syncthreads();
  float s0 = sc_l[w][ll];        // score of row row0+ll (dup across lg)
  float s1 = sc_l[w][ll + 16];

  // apply mask
  const int mbase = bn * KK + row0;
  s0 += (float)masks[mbase + ll] * (-1e9f);
  s1 += (float)masks[mbase + 16 + ll] * (-1e9f);

  // per-wave max (values duplicated across lg -> ll-reduce suffices)
  float mx = fmaxf(s0, s1);
  #pragma unroll
  for (int off = 1; off <= 8; off <<= 1) mx = fmaxf(mx, __shfl_xor(mx, off, 64));

  const float e0 = exp_f(s0 - mx);
  const float e1 = exp_f(s1 - mx);
  float lsum = e0 + e1;
  #pragma unroll
  for (int off = 1; off <= 8; off <<= 1) lsum += __shfl_xor(lsum, off, 64);

  if (lg == 0) {                 // store masked scores (rows row0+ll, +16)
    smask[mbase + ll]      = s0;
    smask[mbase + 16 + ll] = s1;
  }
  if (l == 0) {
    float* mlp = ml_part + ((size_t)bn * 4 + g) * 2;
    mlp[0] = mx;
    mlp[1] = lsum;
  }

  // partial PV in-register: o[e] = e0*keys[row ll][e] + e1*keys[row ll+16][e]
  // lane (lg,ll) holds e = lg*8 + s*32 + j; reduce over ll, lane ll==0 writes.
  float* ob = o_part + ((size_t)bn * 4 + g) * 256;
  #pragma unroll
  for (int s = 0; s < 8; ++s) {
    float pv[8];
    #pragma unroll
    for (int j = 0; j < 8; ++j)
      pv[j] = e0 * bf2f(af0[s][j]) + e1 * bf2f(af1[s][j]);
    #pragma unroll
    for (int j = 0; j < 8; ++j) {
      #pragma unroll
      for (int off = 1; off <= 8; off <<= 1)
        pv[j] += __shfl_xor(pv[j], off, 64);
    }
    if (ll == 0) {
      float4 v0 = {pv[0], pv[1], pv[2], pv[3]};
      float4 v1 = {pv[4], pv[5], pv[6], pv[7]};
      *(float4*)(ob + lg * 8 + s * 32)     = v0;
      *(float4*)(ob + lg * 8 + s * 32 + 4) = v1;
    }
  }
}

// ---------------------------------------------------------------------------
// k_combine: per bn merge 4 flash partials; write attn_out + attn_weight.
//   m = max_g m_g; L = sum_g e^{m_g-m} l_g;
//   out[e] = sum_g e^{m_g-m} o_g[e] / L;  w[k] = e^{s_k-m}/L.
// ---------------------------------------------------------------------------
__global__ __launch_bounds__(256) void k_combine(
    const float* __restrict__ o_part,
    const float* __restrict__ ml_part,
    const float* __restrict__ smask,
    float* __restrict__ out) {
  const int bn = blockIdx.x, t = threadIdx.x;
  __shared__ float al[4];
  __shared__ float mL[2];
  if (t == 0) {
    const float* mlp = ml_part + (size_t)bn * 8;
    float m0 = mlp[0], m1 = mlp[2], m2 = mlp[4], m3 = mlp[6];
    float m = fmaxf(fmaxf(m0, m1), fmaxf(m2, m3));
    float a0 = exp_f(m0 - m), a1 = exp_f(m1 - m);
    float a2 = exp_f(m2 - m), a3 = exp_f(m3 - m);
    al[0] = a0; al[1] = a1; al[2] = a2; al[3] = a3;
    mL[0] = m;
    mL[1] = a0 * mlp[1] + a1 * mlp[3] + a2 * mlp[5] + a3 * mlp[7];
  }
  __syncthreads();
  const float m = mL[0];
  const float invL = __builtin_amdgcn_rcpf(mL[1]);
  const float* ob = o_part + (size_t)bn * 4 * 256;
  float acc = al[0] * ob[t] + al[1] * ob[256 + t] +
              al[2] * ob[512 + t] + al[3] * ob[768 + t];
  out[(size_t)bn * EE + t] = acc * invL;
  if (t < KK)
    out[BN * EE + (size_t)bn * KK + t] = exp_f(smask[bn * KK + t] - m) * invL;
}

// ---------------------------------------------------------------------------
extern "C" void kernel_launch(void* const* d_in, const int* in_sizes, int n_in,
                              void* d_out, int out_size, void* d_ws, size_t ws_size,
                              hipStream_t stream) {
  const float* queries = (const float*)d_in[0];
  const float* keys    = (const float*)d_in[1];
  const int*   masks   = (const int*)d_in[2];
  // d_in[3] = num_neg (unused)
  const float* wk_w = (const float*)d_in[4];
  const float* wk_b = (const float*)d_in[5];
  const float* wq_w = (const float*)d_in[6];
  const float* wq_b = (const float*)d_in[7];
  const float* wv_w = (const float*)d_in[8];
  // d_in[9] = wv_b (softmax shift-invariant -> unused)

  float* out = (float*)d_out;
  float* qp  = (float*)d_ws;                                 // 1 MB
  unsigned short* wk_fr = (unsigned short*)(qp + BN * HH);   // 256 KB
  float* o_part  = (float*)(wk_fr + HH * EE);                // 2 MB
  float* ml_part = o_part + (size_t)BN * 4 * 256;            // 16 KB
  float* smask   = ml_part + BN * 4 * 2;                     // 256 KB

  k_prep<<<128, 256, 0, stream>>>(wk_w, queries, wq_w, wq_b, wk_b, wk_fr, qp);
  k_scorespv<<<BN * 2, 128, 0, stream>>>(keys, wk_fr, wv_w, qp, masks,
                                         o_part, ml_part, smask);
  k_combine<<<BN, 256, 0, stream>>>(o_part, ml_part, smask, out);
}

// Round 13
// 55.762 us; speedup vs baseline: 1.0195x; 1.0195x over previous
//
#include <hip/hip_runtime.h>
#include <hip/hip_bf16.h>

// Problem constants
#define B_  64
#define N1_ 8
#define KK  128
#define EE  256
#define HH  512
#define BN  (B_ * N1_)   // 512

typedef __attribute__((ext_vector_type(8))) short short8;   // bf16x8 MFMA frag
typedef __attribute__((ext_vector_type(4))) float f32x4;    // MFMA acc

__device__ __forceinline__ short bfs(float f) {
  __hip_bfloat16 h = __float2bfloat16(f);   // RNE
  return __builtin_bit_cast(short, h);
}
__device__ __forceinline__ float bf2f(short s) {
  unsigned int u = ((unsigned int)(unsigned short)s) << 16;
  return __builtin_bit_cast(float, u);
}
__device__ __forceinline__ float tanhf_fast(float x) {
  float e2 = __builtin_amdgcn_exp2f(2.8853900817779268f * x);  // exp(2x)
  return 1.0f - 2.0f * __builtin_amdgcn_rcpf(e2 + 1.0f);
}

// async global->LDS, 16 B per lane; LDS dest = wave-uniform base + lane*16
__device__ __forceinline__ void gload16(const void* g, void* l) {
  __builtin_amdgcn_global_load_lds(
      (const __attribute__((address_space(1))) void*)g,
      (__attribute__((address_space(3))) void*)l, 16, 0, 0);
}

// ---------------------------------------------------------------------------
// k_prep:
//  blocks 0..63   -> wk_w -> FRAGMENT-MAJOR bf16 wk_fr:
//     chunk ((ht*8+s)*64 + lane)[8] = wk[ht*16+(lane&15)][(lane>>4)*8+s*32..]
//  blocks 64..127 -> qproj MFMA: qp[bn][h] = q.wq[h] + wq_b[h] + wk_b[h]
// MFMA frag [m89]: A row=lane&15, e=(lane>>4)*8+s*32; D col=lane&15,
// row=(lane>>4)*4+reg.
// ---------------------------------------------------------------------------
__global__ __launch_bounds__(256) void k_prep(
    const float* __restrict__ wk_w,
    const float* __restrict__ queries,
    const float* __restrict__ wq_w,
    const float* __restrict__ wq_b,
    const float* __restrict__ wk_b,
    unsigned short* __restrict__ wk_fr,
    float* __restrict__ qp) {
  const int bid = blockIdx.x, t = threadIdx.x;
  if (bid < 64) {
    const int g  = bid * 256 + t;           // chunk id 0..16383
    const int h  = g >> 5;
    const int e0 = (g & 31) * 8;
    float4 x = *(const float4*)(wk_w + (size_t)h * EE + e0);
    float4 y = *(const float4*)(wk_w + (size_t)h * EE + e0 + 4);
    short8 f;
    f[0] = bfs(x.x); f[1] = bfs(x.y); f[2] = bfs(x.z); f[3] = bfs(x.w);
    f[4] = bfs(y.x); f[5] = bfs(y.y); f[6] = bfs(y.z); f[7] = bfs(y.w);
    const int ht = h >> 4, hl = h & 15;
    const int s = e0 >> 5, lg = (e0 >> 3) & 3;
    const int chunk = (ht * 8 + s) * 64 + lg * 16 + hl;
    *(short8*)(wk_fr + (size_t)chunk * 8) = f;
  } else {
    const int w = t >> 6, l = t & 63, lg = l >> 4, ll = l & 15;
    const int g2 = bid - 64;                // 0..63
    const int bn0 = (g2 >> 1) * 16;
    const int ht0 = (g2 & 1) * 16;
    short8 af[8];
    {
      const float* qr = queries + (size_t)(bn0 + ll) * EE + lg * 8;
      #pragma unroll
      for (int s = 0; s < 8; ++s) {
        float4 x = *(const float4*)(qr + s * 32);
        float4 y = *(const float4*)(qr + s * 32 + 4);
        short8 f;
        f[0] = bfs(x.x); f[1] = bfs(x.y); f[2] = bfs(x.z); f[3] = bfs(x.w);
        f[4] = bfs(y.x); f[5] = bfs(y.y); f[6] = bfs(y.z); f[7] = bfs(y.w);
        af[s] = f;
      }
    }
    #pragma unroll
    for (int i = 0; i < 4; ++i) {
      const int ht = ht0 + w * 4 + i;
      const float* bp = wq_w + (size_t)(ht * 16 + ll) * EE + lg * 8;
      f32x4 a = {0.f, 0.f, 0.f, 0.f};
      #pragma unroll
      for (int s = 0; s < 8; ++s) {
        float4 x = *(const float4*)(bp + s * 32);
        float4 y = *(const float4*)(bp + s * 32 + 4);
        short8 f;
        f[0] = bfs(x.x); f[1] = bfs(x.y); f[2] = bfs(x.z); f[3] = bfs(x.w);
        f[4] = bfs(y.x); f[5] = bfs(y.y); f[6] = bfs(y.z); f[7] = bfs(y.w);
        a = __builtin_amdgcn_mfma_f32_16x16x32_bf16(af[s], f, a, 0, 0, 0);
      }
      const int h = ht * 16 + ll;
      const float add = wq_b[h] + wk_b[h];
      #pragma unroll
      for (int r = 0; r < 4; ++r)
        qp[(size_t)(bn0 + lg * 4 + r) * HH + h] = a[r] + add;
    }
  }
}

// ---------------------------------------------------------------------------
// k_fused: one block = one bn. 4 waves x 32 rows; every wave covers all 512 h.
// Keys read ONCE (A-frags in regs; PV computed from them in-register).
// B: 3-deep LDS ring (3 x 8 KB), global_load_lds staged 2 tiles ahead,
// counted s_waitcnt vmcnt(2) + RAW s_barrier (no drain) + sched_barrier(0).
// Stage for tile i+2 issued AFTER barrier(i): laggards are in compute(i-1)
// reading buf[(i-1)%3]; (i+2)%3 == (i-1)%3 is avoided because stage comes
// after the barrier that retires compute(i-1) block-wide.
// B L2 traffic: 512 blocks x 256 KB = 128 MB. Softmax + PV fused in-block.
// MFMA 16x16x32 C/D: col(h)=lane&15, row(key)=(lane>>4)*4+reg   [m89].
// ---------------------------------------------------------------------------
__global__ __launch_bounds__(256, 2) void k_fused(
    const float* __restrict__ keys,
    const unsigned short* __restrict__ wk_fr,
    const float* __restrict__ wv_w,
    const float* __restrict__ qp,
    const int* __restrict__ masks,
    float* __restrict__ out) {
  const int t  = threadIdx.x;
  const int w  = t >> 6;      // wave 0..3
  const int l  = t & 63;
  const int lg = l >> 4;      // lane group 0..3
  const int ll = l & 15;
  const int bn = blockIdx.x;

  __shared__ __align__(16) char bsm[3 * 8192];   // B tile ring
  __shared__ float qb_s[HH];
  __shared__ float wv_s[HH];
  __shared__ float sc[KK];
  __shared__ float red[2];
  __shared__ float po[4][256];

  qb_s[t]       = qp[(size_t)bn * HH + t];
  qb_s[t + 256] = qp[(size_t)bn * HH + t + 256];
  wv_s[t]       = wv_w[t];
  wv_s[t + 256] = wv_w[t + 256];

  // this wave's 32 rows -> bf16 A-frags (2 chains x 8 slots), kept for PV
  short8 af0[8], af1[8];
  {
    const float* kp0 = keys + (size_t)(bn * KK + w * 32 + ll) * EE + lg * 8;
    const float* kp1 = kp0 + 16 * EE;
    #pragma unroll
    for (int s = 0; s < 8; ++s) {
      float4 x = *(const float4*)(kp0 + s * 32);
      float4 y = *(const float4*)(kp0 + s * 32 + 4);
      short8 f;
      f[0] = bfs(x.x); f[1] = bfs(x.y); f[2] = bfs(x.z); f[3] = bfs(x.w);
      f[4] = bfs(y.x); f[5] = bfs(y.y); f[6] = bfs(y.z); f[7] = bfs(y.w);
      af0[s] = f;
      x = *(const float4*)(kp1 + s * 32);
      y = *(const float4*)(kp1 + s * 32 + 4);
      f[0] = bfs(x.x); f[1] = bfs(x.y); f[2] = bfs(x.z); f[3] = bfs(x.w);
      f[4] = bfs(y.x); f[5] = bfs(y.y); f[6] = bfs(y.z); f[7] = bfs(y.w);
      af1[s] = f;
    }
  }
  __syncthreads();   // qb_s/wv_s visible (full drain OK here, pre-pipeline)

  const char* wkb = (const char*)wk_fr;   // 32 tiles x 8192 B, fragment-major

#define STAGE(ti, off) {                                                     \
    const char* s_ = wkb + (size_t)(ti) * 8192 + (size_t)t * 16;             \
    char* d_ = bsm + (off) + w * 1024;                                       \
    gload16(s_, d_);                                                         \
    gload16(s_ + 4096, d_ + 4096); }

  // prologue: stage tiles 0,1 -> 4 outstanding vmem ops per thread
  STAGE(0, 0);
  STAGE(1, 8192);

  float p0[4] = {0.f, 0.f, 0.f, 0.f};
  float p1[4] = {0.f, 0.f, 0.f, 0.f};
  int off0 = 0, off1 = 8192, off2 = 16384;   // read, next, stage targets

#define COMPUTE(roff, ii) {                                                  \
    f32x4 a0 = {0.f, 0.f, 0.f, 0.f};                                         \
    f32x4 a1 = {0.f, 0.f, 0.f, 0.f};                                         \
    __builtin_amdgcn_s_setprio(1);                                           \
    _Pragma("unroll") for (int s = 0; s < 8; ++s) {                          \
      short8 bfr = *(const short8*)(bsm + (roff) + s * 1024 + l * 16);       \
      a0 = __builtin_amdgcn_mfma_f32_16x16x32_bf16(af0[s], bfr, a0, 0, 0, 0);\
      a1 = __builtin_amdgcn_mfma_f32_16x16x32_bf16(af1[s], bfr, a1, 0, 0, 0);\
    }                                                                        \
    __builtin_amdgcn_s_setprio(0);                                           \
    const int h = (ii) * 16 + ll;                                            \
    const float qb = qb_s[h];                                                \
    const float wv = wv_s[h];                                                \
    _Pragma("unroll") for (int r = 0; r < 4; ++r) {                          \
      p0[r] += wv * tanhf_fast(a0[r] + qb);                                  \
      p1[r] += wv * tanhf_fast(a1[r] + qb); } }

  #pragma unroll 1
  for (int i = 0; i < 30; ++i) {
    asm volatile("s_waitcnt vmcnt(2)" ::: "memory");  // stage(i) landed
    __builtin_amdgcn_s_barrier();                      // raw: no drain
    __builtin_amdgcn_sched_barrier(0);
    STAGE(i + 2, off2);                                // safe: all past bar(i)
    COMPUTE(off0, i);
    int tmp = off0; off0 = off1; off1 = off2; off2 = tmp;
  }
  // peeled tail: i = 30 (stage(31) still outstanding), i = 31 (drain)
  asm volatile("s_waitcnt vmcnt(2)" ::: "memory");
  __builtin_amdgcn_s_barrier();
  __builtin_amdgcn_sched_barrier(0);
  COMPUTE(off0, 30);
  { int tmp = off0; off0 = off1; off1 = off2; off2 = tmp; }
  asm volatile("s_waitcnt vmcnt(0)" ::: "memory");
  __builtin_amdgcn_s_barrier();
  __builtin_amdgcn_sched_barrier(0);
  COMPUTE(off0, 31);
#undef COMPUTE
#undef STAGE

  // reduce scores over h (16 ll lanes per group)
  #pragma unroll
  for (int r = 0; r < 4; ++r) {
    #pragma unroll
    for (int off = 1; off <= 8; off <<= 1) {
      p0[r] += __shfl_xor(p0[r], off, 64);
      p1[r] += __shfl_xor(p1[r], off, 64);
    }
  }
  if (ll == 0) {
    #pragma unroll
    for (int r = 0; r < 4; ++r) {
      sc[w * 32 + lg * 4 + r]      = p0[r];
      sc[w * 32 + 16 + lg * 4 + r] = p1[r];
    }
  }
  __syncthreads();

  // masked softmax over K=128 (wv_b omitted: softmax shift-invariant)
  if (t < KK) sc[t] += (float)masks[bn * KK + t] * (-1e9f);
  __syncthreads();
  if (t < 64) {
    float a = fmaxf(sc[t], sc[t + 64]);
    #pragma unroll
    for (int off = 32; off >= 1; off >>= 1) a = fmaxf(a, __shfl_xor(a, off, 64));
    if (t == 0) red[0] = a;
  }
  __syncthreads();
  const float m = red[0];
  if (t < KK) sc[t] = expf(sc[t] - m);
  __syncthreads();
  if (t < 64) {
    float a = sc[t] + sc[t + 64];
    #pragma unroll
    for (int off = 32; off >= 1; off >>= 1) a += __shfl_xor(a, off, 64);
    if (t == 0) red[1] = a;
  }
  __syncthreads();
  const float inv = 1.f / red[1];
  if (t < KK) {
    float wgt = sc[t] * inv;
    sc[t] = wgt;
    out[BN * EE + (size_t)bn * KK + t] = wgt;   // attn_weight
  }
  __syncthreads();

  // PV in-register from A-frags: lane (lg,ll) holds rows w*32+ll, w*32+16+ll
  // at e = lg*8 + s*32 + j. Reduce over ll -> po[w][e]; then sum waves.
  {
    const float wgt0 = sc[w * 32 + ll];
    const float wgt1 = sc[w * 32 + 16 + ll];
    #pragma unroll
    for (int s = 0; s < 8; ++s) {
      float pv[8];
      #pragma unroll
      for (int j = 0; j < 8; ++j)
        pv[j] = wgt0 * bf2f(af0[s][j]) + wgt1 * bf2f(af1[s][j]);
      #pragma unroll
      for (int j = 0; j < 8; ++j) {
        #pragma unroll
        for (int off = 1; off <= 8; off <<= 1)
          pv[j] += __shfl_xor(pv[j], off, 64);
      }
      if (ll == 0) {
        float4 v0 = {pv[0], pv[1], pv[2], pv[3]};
        float4 v1 = {pv[4], pv[5], pv[6], pv[7]};
        *(float4*)(&po[w][lg * 8 + s * 32])     = v0;
        *(float4*)(&po[w][lg * 8 + s * 32 + 4]) = v1;
      }
    }
  }
  __syncthreads();
  out[(size_t)bn * EE + t] = po[0][t] + po[1][t] + po[2][t] + po[3][t];
}

// ---------------------------------------------------------------------------
extern "C" void kernel_launch(void* const* d_in, const int* in_sizes, int n_in,
                              void* d_out, int out_size, void* d_ws, size_t ws_size,
                              hipStream_t stream) {
  const float* queries = (const float*)d_in[0];
  const float* keys    = (const float*)d_in[1];
  const int*   masks   = (const int*)d_in[2];
  // d_in[3] = num_neg (unused)
  const float* wk_w = (const float*)d_in[4];
  const float* wk_b = (const float*)d_in[5];
  const float* wq_w = (const float*)d_in[6];
  const float* wq_b = (const float*)d_in[7];
  const float* wv_w = (const float*)d_in[8];
  // d_in[9] = wv_b (softmax shift-invariant -> unused)

  float* out = (float*)d_out;
  float* qp  = (float*)d_ws;                                 // 1 MB
  unsigned short* wk_fr = (unsigned short*)(qp + BN * HH);   // 256 KB

  k_prep<<<128, 256, 0, stream>>>(wk_w, queries, wq_w, wq_b, wk_b, wk_fr, qp);
  k_fused<<<BN, 256, 0, stream>>>(keys, wk_fr, wv_w, qp, masks, out);
}

// Round 17
// 49.823 us; speedup vs baseline: 1.1410x; 1.1192x over previous
//
#include <hip/hip_runtime.h>
#include <hip/hip_bf16.h>

// Problem constants
#define B_  64
#define N1_ 8
#define KK  128
#define EE  256
#define HH  512
#define BN  (B_ * N1_)   // 512

typedef __attribute__((ext_vector_type(8))) short short8;   // bf16x8 MFMA frag
typedef __attribute__((ext_vector_type(4))) float f32x4;    // MFMA acc

__device__ __forceinline__ short bfs(float f) {
  __hip_bfloat16 h = __float2bfloat16(f);   // RNE
  return __builtin_bit_cast(short, h);
}
__device__ __forceinline__ float bf2f(short s) {
  unsigned int u = ((unsigned int)(unsigned short)s) << 16;
  return __builtin_bit_cast(float, u);
}
__device__ __forceinline__ float tanhf_fast(float x) {
  float e2 = __builtin_amdgcn_exp2f(2.8853900817779268f * x);  // exp(2x)
  return 1.0f - 2.0f * __builtin_amdgcn_rcpf(e2 + 1.0f);
}

// ---------------------------------------------------------------------------
// k_prep:
//  blocks 0..63   -> wk_w -> FRAGMENT-MAJOR bf16 wk_fr:
//     chunk ((ht*8+s)*64 + lane)[8] = wk[ht*16+(lane&15)][(lane>>4)*8+s*32..]
//  blocks 64..127 -> qproj MFMA: qp[bn][h] = q.wq[h] + wq_b[h] + wk_b[h]
// MFMA frag [m89]: A row=lane&15, e=(lane>>4)*8+s*32; D col=lane&15,
// row=(lane>>4)*4+reg.
// ---------------------------------------------------------------------------
__global__ __launch_bounds__(256) void k_prep(
    const float* __restrict__ wk_w,
    const float* __restrict__ queries,
    const float* __restrict__ wq_w,
    const float* __restrict__ wq_b,
    const float* __restrict__ wk_b,
    unsigned short* __restrict__ wk_fr,
    float* __restrict__ qp) {
  const int bid = blockIdx.x, t = threadIdx.x;
  if (bid < 64) {
    const int g  = bid * 256 + t;           // chunk id 0..16383
    const int h  = g >> 5;
    const int e0 = (g & 31) * 8;
    float4 x = *(const float4*)(wk_w + (size_t)h * EE + e0);
    float4 y = *(const float4*)(wk_w + (size_t)h * EE + e0 + 4);
    short8 f;
    f[0] = bfs(x.x); f[1] = bfs(x.y); f[2] = bfs(x.z); f[3] = bfs(x.w);
    f[4] = bfs(y.x); f[5] = bfs(y.y); f[6] = bfs(y.z); f[7] = bfs(y.w);
    const int ht = h >> 4, hl = h & 15;
    const int s = e0 >> 5, lg = (e0 >> 3) & 3;
    const int chunk = (ht * 8 + s) * 64 + lg * 16 + hl;
    *(short8*)(wk_fr + (size_t)chunk * 8) = f;
  } else {
    const int w = t >> 6, l = t & 63, lg = l >> 4, ll = l & 15;
    const int g2 = bid - 64;                // 0..63
    const int bn0 = (g2 >> 1) * 16;
    const int ht0 = (g2 & 1) * 16;
    short8 af[8];
    {
      const float* qr = queries + (size_t)(bn0 + ll) * EE + lg * 8;
      #pragma unroll
      for (int s = 0; s < 8; ++s) {
        float4 x = *(const float4*)(qr + s * 32);
        float4 y = *(const float4*)(qr + s * 32 + 4);
        short8 f;
        f[0] = bfs(x.x); f[1] = bfs(x.y); f[2] = bfs(x.z); f[3] = bfs(x.w);
        f[4] = bfs(y.x); f[5] = bfs(y.y); f[6] = bfs(y.z); f[7] = bfs(y.w);
        af[s] = f;
      }
    }
    #pragma unroll
    for (int i = 0; i < 4; ++i) {
      const int ht = ht0 + w * 4 + i;
      const float* bp = wq_w + (size_t)(ht * 16 + ll) * EE + lg * 8;
      f32x4 a = {0.f, 0.f, 0.f, 0.f};
      #pragma unroll
      for (int s = 0; s < 8; ++s) {
        float4 x = *(const float4*)(bp + s * 32);
        float4 y = *(const float4*)(bp + s * 32 + 4);
        short8 f;
        f[0] = bfs(x.x); f[1] = bfs(x.y); f[2] = bfs(x.z); f[3] = bfs(x.w);
        f[4] = bfs(y.x); f[5] = bfs(y.y); f[6] = bfs(y.z); f[7] = bfs(y.w);
        a = __builtin_amdgcn_mfma_f32_16x16x32_bf16(af[s], f, a, 0, 0, 0);
      }
      const int h = ht * 16 + ll;
      const float add = wq_b[h] + wk_b[h];
      #pragma unroll
      for (int r = 0; r < 4; ++r)
        qp[(size_t)(bn0 + lg * 4 + r) * HH + h] = a[r] + add;
    }
  }
}

// ---------------------------------------------------------------------------
// k_fused: one block = one bn. 4 waves x 32 rows; every wave covers all 512 h.
// Keys read ONCE (A-frags in regs; PV computed from them in-register).
// B: hand-held ASM register pipeline, 2 tiles deep. Loads are inline-asm
// global_load_dwordx4 with EARLY-CLOBBER "=&v" outputs (async writeback must
// not alias the address regs — plain "=v" caused the round-16 device fault).
// Release-wait = bare s_waitcnt vmcnt(N) + sched_barrier(0) (rule #18).
// NO barriers in the loop: 4 waves drift, share B stream through L1.
// MFMA 16x16x32 C/D: col(h)=lane&15, row(key)=(lane>>4)*4+reg   [m89].
// ---------------------------------------------------------------------------
__global__ __launch_bounds__(256, 2) void k_fused(
    const float* __restrict__ keys,
    const unsigned short* __restrict__ wk_fr,
    const float* __restrict__ wv_w,
    const float* __restrict__ qp,
    const int* __restrict__ masks,
    float* __restrict__ out) {
  const int t  = threadIdx.x;
  const int w  = t >> 6;      // wave 0..3
  const int l  = t & 63;
  const int lg = l >> 4;      // lane group 0..3
  const int ll = l & 15;
  const int bn = blockIdx.x;

  __shared__ float2 qw_s[HH];     // {qb, wv} per h
  __shared__ float sc[KK];
  __shared__ float red[2];
  __shared__ float po[4][256];

  {
    float2 v0; v0.x = qp[(size_t)bn * HH + t];       v0.y = wv_w[t];
    float2 v1; v1.x = qp[(size_t)bn * HH + t + 256]; v1.y = wv_w[t + 256];
    qw_s[t] = v0;
    qw_s[t + 256] = v1;
  }

  // this wave's 32 rows -> bf16 A-frags (2 chains x 8 slots), kept for PV
  short8 af0[8], af1[8];
  {
    const float* kp0 = keys + (size_t)(bn * KK + w * 32 + ll) * EE + lg * 8;
    const float* kp1 = kp0 + 16 * EE;
    #pragma unroll
    for (int s = 0; s < 8; ++s) {
      float4 x = *(const float4*)(kp0 + s * 32);
      float4 y = *(const float4*)(kp0 + s * 32 + 4);
      short8 f;
      f[0] = bfs(x.x); f[1] = bfs(x.y); f[2] = bfs(x.z); f[3] = bfs(x.w);
      f[4] = bfs(y.x); f[5] = bfs(y.y); f[6] = bfs(y.z); f[7] = bfs(y.w);
      af0[s] = f;
      x = *(const float4*)(kp1 + s * 32);
      y = *(const float4*)(kp1 + s * 32 + 4);
      f[0] = bfs(x.x); f[1] = bfs(x.y); f[2] = bfs(x.z); f[3] = bfs(x.w);
      f[4] = bfs(y.x); f[5] = bfs(y.y); f[6] = bfs(y.z); f[7] = bfs(y.w);
      af1[s] = f;
    }
  }
  __syncthreads();   // qw_s visible; drains all counters -> clean vmcnt slate

  const char* wkb = (const char*)wk_fr;   // 32 tiles x 8192 B, fragment-major
  const int lofs = l * 16;

  float p0[4] = {0.f, 0.f, 0.f, 0.f};
  float p1[4] = {0.f, 0.f, 0.f, 0.f};
  float4 A0, A1, A2, A3, A4, A5, A6, A7;
  float4 B0, B1, B2, B3, B4, B5, B6, B7;

#define ISSUE(b0,b1,b2,b3,b4,b5,b6,b7, ti) {                               \
    const char* p_ = wkb + (size_t)(ti) * 8192 + lofs;                     \
    const char* q_ = p_ + 4096;                                            \
    asm volatile(                                                          \
      "global_load_dwordx4 %0, %8, off\n\t"                                \
      "global_load_dwordx4 %1, %8, off offset:1024\n\t"                    \
      "global_load_dwordx4 %2, %8, off offset:2048\n\t"                    \
      "global_load_dwordx4 %3, %8, off offset:3072\n\t"                    \
      "global_load_dwordx4 %4, %9, off\n\t"                                \
      "global_load_dwordx4 %5, %9, off offset:1024\n\t"                    \
      "global_load_dwordx4 %6, %9, off offset:2048\n\t"                    \
      "global_load_dwordx4 %7, %9, off offset:3072"                        \
      : "=&v"(b0), "=&v"(b1), "=&v"(b2), "=&v"(b3),                        \
        "=&v"(b4), "=&v"(b5), "=&v"(b6), "=&v"(b7)                        \
      : "v"(p_), "v"(q_)); }

#define WAITV(n)  {                                                        \
    asm volatile("s_waitcnt vmcnt(" #n ")" ::: "memory");                  \
    __builtin_amdgcn_sched_barrier(0); }

#define COMPUTE(b0,b1,b2,b3,b4,b5,b6,b7, ii) {                             \
    f32x4 a0 = {0.f, 0.f, 0.f, 0.f};                                       \
    f32x4 a1 = {0.f, 0.f, 0.f, 0.f};                                       \
    short8 f_;                                                             \
    __builtin_amdgcn_s_setprio(1);                                         \
    f_ = __builtin_bit_cast(short8, b0);                                   \
    a0 = __builtin_amdgcn_mfma_f32_16x16x32_bf16(af0[0], f_, a0, 0, 0, 0); \
    a1 = __builtin_amdgcn_mfma_f32_16x16x32_bf16(af1[0], f_, a1, 0, 0, 0); \
    f_ = __builtin_bit_cast(short8, b1);                                   \
    a0 = __builtin_amdgcn_mfma_f32_16x16x32_bf16(af0[1], f_, a0, 0, 0, 0); \
    a1 = __builtin_amdgcn_mfma_f32_16x16x32_bf16(af1[1], f_, a1, 0, 0, 0); \
    f_ = __builtin_bit_cast(short8, b2);                                   \
    a0 = __builtin_amdgcn_mfma_f32_16x16x32_bf16(af0[2], f_, a0, 0, 0, 0); \
    a1 = __builtin_amdgcn_mfma_f32_16x16x32_bf16(af1[2], f_, a1, 0, 0, 0); \
    f_ = __builtin_bit_cast(short8, b3);                                   \
    a0 = __builtin_amdgcn_mfma_f32_16x16x32_bf16(af0[3], f_, a0, 0, 0, 0); \
    a1 = __builtin_amdgcn_mfma_f32_16x16x32_bf16(af1[3], f_, a1, 0, 0, 0); \
    f_ = __builtin_bit_cast(short8, b4);                                   \
    a0 = __builtin_amdgcn_mfma_f32_16x16x32_bf16(af0[4], f_, a0, 0, 0, 0); \
    a1 = __builtin_amdgcn_mfma_f32_16x16x32_bf16(af1[4], f_, a1, 0, 0, 0); \
    f_ = __builtin_bit_cast(short8, b5);                                   \
    a0 = __builtin_amdgcn_mfma_f32_16x16x32_bf16(af0[5], f_, a0, 0, 0, 0); \
    a1 = __builtin_amdgcn_mfma_f32_16x16x32_bf16(af1[5], f_, a1, 0, 0, 0); \
    f_ = __builtin_bit_cast(short8, b6);                                   \
    a0 = __builtin_amdgcn_mfma_f32_16x16x32_bf16(af0[6], f_, a0, 0, 0, 0); \
    a1 = __builtin_amdgcn_mfma_f32_16x16x32_bf16(af1[6], f_, a1, 0, 0, 0); \
    f_ = __builtin_bit_cast(short8, b7);                                   \
    a0 = __builtin_amdgcn_mfma_f32_16x16x32_bf16(af0[7], f_, a0, 0, 0, 0); \
    a1 = __builtin_amdgcn_mfma_f32_16x16x32_bf16(af1[7], f_, a1, 0, 0, 0); \
    __builtin_amdgcn_s_setprio(0);                                         \
    const float2 qw = qw_s[(ii) * 16 + ll];                                \
    _Pragma("unroll") for (int r = 0; r < 4; ++r) {                        \
      p0[r] += qw.y * tanhf_fast(a0[r] + qw.x);                            \
      p1[r] += qw.y * tanhf_fast(a1[r] + qw.x); } }

  ISSUE(A0,A1,A2,A3,A4,A5,A6,A7, 0);
  ISSUE(B0,B1,B2,B3,B4,B5,B6,B7, 1);
  #pragma unroll 1
  for (int i = 0; i < 30; i += 2) {
    WAITV(8);                                 // tile i landed
    COMPUTE(A0,A1,A2,A3,A4,A5,A6,A7, i);
    ISSUE(A0,A1,A2,A3,A4,A5,A6,A7, i + 2);
    WAITV(8);                                 // tile i+1 landed
    COMPUTE(B0,B1,B2,B3,B4,B5,B6,B7, i + 1);
    ISSUE(B0,B1,B2,B3,B4,B5,B6,B7, i + 3);
  }
  WAITV(8);                                   // tile 30
  COMPUTE(A0,A1,A2,A3,A4,A5,A6,A7, 30);
  WAITV(0);                                   // tile 31 (drain)
  COMPUTE(B0,B1,B2,B3,B4,B5,B6,B7, 31);
#undef COMPUTE
#undef WAITV
#undef ISSUE

  // reduce scores over h (16 ll lanes per group)
  #pragma unroll
  for (int r = 0; r < 4; ++r) {
    #pragma unroll
    for (int off = 1; off <= 8; off <<= 1) {
      p0[r] += __shfl_xor(p0[r], off, 64);
      p1[r] += __shfl_xor(p1[r], off, 64);
    }
  }
  if (ll == 0) {
    #pragma unroll
    for (int r = 0; r < 4; ++r) {
      sc[w * 32 + lg * 4 + r]      = p0[r];
      sc[w * 32 + 16 + lg * 4 + r] = p1[r];
    }
  }
  __syncthreads();

  // masked softmax over K=128 (wv_b omitted: softmax shift-invariant)
  if (t < KK) sc[t] += (float)masks[bn * KK + t] * (-1e9f);
  __syncthreads();
  if (t < 64) {
    float a = fmaxf(sc[t], sc[t + 64]);
    #pragma unroll
    for (int off = 32; off >= 1; off >>= 1) a = fmaxf(a, __shfl_xor(a, off, 64));
    if (t == 0) red[0] = a;
  }
  __syncthreads();
  const float m = red[0];
  if (t < KK) sc[t] = expf(sc[t] - m);
  __syncthreads();
  if (t < 64) {
    float a = sc[t] + sc[t + 64];
    #pragma unroll
    for (int off = 32; off >= 1; off >>= 1) a += __shfl_xor(a, off, 64);
    if (t == 0) red[1] = a;
  }
  __syncthreads();
  const float inv = 1.f / red[1];
  if (t < KK) {
    float wgt = sc[t] * inv;
    sc[t] = wgt;
    out[BN * EE + (size_t)bn * KK + t] = wgt;   // attn_weight
  }
  __syncthreads();

  // PV in-register from A-frags: lane (lg,ll) holds rows w*32+ll, w*32+16+ll
  // at e = lg*8 + s*32 + j. Reduce over ll -> po[w][e]; then sum waves.
  {
    const float wgt0 = sc[w * 32 + ll];
    const float wgt1 = sc[w * 32 + 16 + ll];
    #pragma unroll
    for (int s = 0; s < 8; ++s) {
      float pv[8];
      #pragma unroll
      for (int j = 0; j < 8; ++j)
        pv[j] = wgt0 * bf2f(af0[s][j]) + wgt1 * bf2f(af1[s][j]);
      #pragma unroll
      for (int j = 0; j < 8; ++j) {
        #pragma unroll
        for (int off = 1; off <= 8; off <<= 1)
          pv[j] += __shfl_xor(pv[j], off, 64);
      }
      if (ll == 0) {
        float4 v0 = {pv[0], pv[1], pv[2], pv[3]};
        float4 v1 = {pv[4], pv[5], pv[6], pv[7]};
        *(float4*)(&po[w][lg * 8 + s * 32])     = v0;
        *(float4*)(&po[w][lg * 8 + s * 32 + 4]) = v1;
      }
    }
  }
  __syncthreads();
  out[(size_t)bn * EE + t] = po[0][t] + po[1][t] + po[2][t] + po[3][t];
}

// ---------------------------------------------------------------------------
extern "C" void kernel_launch(void* const* d_in, const int* in_sizes, int n_in,
                              void* d_out, int out_size, void* d_ws, size_t ws_size,
                              hipStream_t stream) {
  const float* queries = (const float*)d_in[0];
  const float* keys    = (const float*)d_in[1];
  const int*   masks   = (const int*)d_in[2];
  // d_in[3] = num_neg (unused)
  const float* wk_w = (const float*)d_in[4];
  const float* wk_b = (const float*)d_in[5];
  const float* wq_w = (const float*)d_in[6];
  const float* wq_b = (const float*)d_in[7];
  const float* wv_w = (const float*)d_in[8];
  // d_in[9] = wv_b (softmax shift-invariant -> unused)

  float* out = (float*)d_out;
  float* qp  = (float*)d_ws;                                 // 1 MB
  unsigned short* wk_fr = (unsigned short*)(qp + BN * HH);   // 256 KB

  k_prep<<<128, 256, 0, stream>>>(wk_w, queries, wq_w, wq_b, wk_b, wk_fr, qp);
  k_fused<<<BN, 256, 0, stream>>>(keys, wk_fr, wv_w, qp, masks, out);
}